// Round 13
// baseline (175.763 us; speedup 1.0000x reference)
//
#include <hip/hip_runtime.h>
#include <hip/hip_bf16.h>

typedef __attribute__((ext_vector_type(8))) short short8;
typedef float floatx4 __attribute__((ext_vector_type(4)));
typedef float floatx16 __attribute__((ext_vector_type(16)));

#define LQ 4096
#define LK 1024
#define NH 24
#define HD 128
#define HID 3072

__device__ __forceinline__ unsigned short f2bf(float f) {
    __hip_bfloat16 h = __float2bfloat16(f);
    union { __hip_bfloat16 b; unsigned short u; } c; c.b = h;
    return c.u;
}

// pack two f32 -> packed 2x bf16 in one instr (RNE)
__device__ __forceinline__ unsigned cvtpk(float a, float b) {
    unsigned r;
    asm("v_cvt_pk_bf16_f32 %0, %1, %2" : "=v"(r) : "v"(a), "v"(b));
    return r;
}

// async global->LDS, 16B per lane. LDS dest must be wave-uniform base (HW adds lane*16).
__device__ __forceinline__ void gload16(const void* g, void* l) {
    __builtin_amdgcn_global_load_lds(
        (const __attribute__((address_space(1))) void*)g,
        (__attribute__((address_space(3))) void*)l,
        16, 0, 0);
}

// ---------------- f32 -> bf16 convert ----------------
__global__ void f32_to_bf16(const float* __restrict__ in, unsigned short* __restrict__ out, int n4) {
    int i = blockIdx.x * blockDim.x + threadIdx.x;
    int stride = gridDim.x * blockDim.x;
    for (; i < n4; i += stride) {
        float4 v = ((const float4*)in)[i];
        ushort4 o;
        o.x = f2bf(v.x); o.y = f2bf(v.y); o.z = f2bf(v.z); o.w = f2bf(v.w);
        ((ushort4*)out)[i] = o;
    }
}

// ---------------- bf16 GEMM, split-K=2 (proven round-8 structure) ----------------
__global__ __launch_bounds__(256) void gemm_proj(const unsigned short* __restrict__ A,
                                                 const unsigned short* __restrict__ Bw,
                                                 float* __restrict__ C,
                                                 int M, int N, int K) {
    __shared__ __align__(16) unsigned short As[2][64 * 64];
    __shared__ __align__(16) unsigned short Bs[2][128 * 64];
    const int tid = threadIdx.x;
    const int lane = tid & 63;
    const int wave = tid >> 6;
    const int wm = wave >> 1, wn = wave & 1;
    const int flat = blockIdx.x + gridDim.x * blockIdx.y;  // 0..383 within z-slice
    const int wid = (flat & 7) * 48 + (flat >> 3);         // XCD-contiguous
    const int bm0 = (wid & 15) * 64;
    const int bn0 = (wid >> 4) * 128;
    const int kbeg = blockIdx.z * (K >> 1);
    const int kend = kbeg + (K >> 1);
    float* Cz = C + (size_t)blockIdx.z * M * N;
    const int lr = lane & 15;
    const int lg = lane >> 4;

    floatx4 acc[2][4];
    for (int i = 0; i < 2; ++i)
        for (int j = 0; j < 4; ++j)
            acc[i][j] = (floatx4){0.f, 0.f, 0.f, 0.f};

    auto stage = [&](int b, int k0) {
        for (int p = 0; p < 2; ++p) {
            int slot = p * 256 + tid;
            int r = slot >> 3, cb = slot & 7;
            int g = cb ^ (r & 7);
            gload16(&A[(bm0 + r) * K + k0 + g * 8], &As[b][(p * 256 + wave * 64) * 8]);
        }
        for (int p = 0; p < 4; ++p) {
            int slot = p * 256 + tid;
            int r = slot >> 3, cb = slot & 7;
            int g = cb ^ (r & 7);
            gload16(&Bw[(bn0 + r) * K + k0 + g * 8], &Bs[b][(p * 256 + wave * 64) * 8]);
        }
    };

    auto compute = [&](int b) {
        for (int ks = 0; ks < 2; ++ks) {
            short8 af[2], bfr[4];
            for (int mt = 0; mt < 2; ++mt) {
                int m = wm * 32 + mt * 16 + lr;
                int sc = (ks * 4 + lg) ^ (m & 7);
                af[mt] = *(const short8*)(&As[b][m * 64 + sc * 8]);
            }
            for (int nt = 0; nt < 4; ++nt) {
                int n = wn * 64 + nt * 16 + lr;
                int sc = (ks * 4 + lg) ^ (n & 7);
                bfr[nt] = *(const short8*)(&Bs[b][n * 64 + sc * 8]);
            }
            for (int mt = 0; mt < 2; ++mt)
                for (int nt = 0; nt < 4; ++nt)
                    acc[mt][nt] = __builtin_amdgcn_mfma_f32_16x16x32_bf16(af[mt], bfr[nt], acc[mt][nt], 0, 0, 0);
        }
    };

    stage(0, kbeg);
    __syncthreads();
    int buf = 0;
    for (int k0 = kbeg; k0 < kend - 64; k0 += 64) {
        stage(buf ^ 1, k0 + 64);
        compute(buf);
        __syncthreads();
        buf ^= 1;
    }
    compute(buf);

    for (int mt = 0; mt < 2; ++mt)
        for (int nt = 0; nt < 4; ++nt)
            for (int rg = 0; rg < 4; ++rg) {
                int m = bm0 + wm * 32 + mt * 16 + lg * 4 + rg;
                int n = bn0 + wn * 64 + nt * 16 + lr;
                Cz[m * N + n] = acc[mt][nt][rg];
            }
}

// ---------------- RMSNorm + RoPE on K (reads two split-K partials) ----------------
__global__ __launch_bounds__(256) void rmsnorm_rope(const float* __restrict__ r0,
                                                    const float* __restrict__ r1,
                                                    const float* __restrict__ freqs,
                                                    const float* __restrict__ w,
                                                    unsigned short* __restrict__ Kbf) {
    int row = blockIdx.x * 2 + (threadIdx.x >> 7);  // l*NH + h
    int l = row / NH, h = row % NH;
    int d = threadIdx.x & 127;
    int idx = l * HID + h * HD + d;
    float x = r0[idx] + r1[idx];
    float ss = x * x;
    for (int off = 32; off; off >>= 1) ss += __shfl_xor(ss, off);
    __shared__ float red[4];
    int wv = threadIdx.x >> 6;
    if ((threadIdx.x & 63) == 0) red[wv] = ss;
    __syncthreads();
    int base = (threadIdx.x >> 7) * 2;
    float tot = red[base] + red[base + 1];
    float rsn = rsqrtf(tot * (1.0f / 128.0f) + 1e-6f);
    float xn = x * rsn * w[d];
    float f = freqs[l * (HD / 2) + (d >> 1)];
    float s = __sinf(f), c = __cosf(f);   // freqs in [0,1): no range reduction needed
    float partner = __shfl_xor(xn, 1);
    float o = (d & 1) ? (partner * s + xn * c) : (xn * c - partner * s);
    Kbf[idx] = f2bf(o);
}

// ---------------- V transpose -> FRAGMENT-ORDER global layout (32-key tiles) ----
// Vfrag[h][kt32][ntd][c][hi][l31]: 16B vector = bf16 V[kt32*32 + c*16 + hi*8 + j]
// [hd = h*128 + ntd*32 + l31]. One head+ktile = contiguous 8KB -> attn stages it
// with 2 linear gload16; reads hit 32 consecutive slots (conflict-free).
__global__ __launch_bounds__(256) void transpose_v(const float* __restrict__ r0,
                                                   const float* __restrict__ r1,
                                                   unsigned short* __restrict__ Vfrag) {
    __shared__ float tile[32][65];
    const int bx = blockIdx.x;          // hd0/64: 0..47
    const int by = blockIdx.y;          // kt32: 0..31
    const int hd0 = bx * 64, l0 = by * 32;
    const int tx = threadIdx.x & 63;
    const int tg8 = threadIdx.x >> 6;   // 0..3
    for (int i = 0; i < 8; ++i) {
        int r = tg8 * 8 + i;
        int idx = (l0 + r) * HID + hd0 + tx;
        tile[r][tx] = r0[idx] + r1[idx];
    }
    __syncthreads();
    const int tg = threadIdx.x >> 6;    // 0..3
    const int c = tg >> 1, hi = tg & 1;
    const int hdl = threadIdx.x & 63;
    const int kloc = c * 16 + hi * 8;
    short8 v;
    for (int j = 0; j < 8; ++j)
        v[j] = (short)f2bf(tile[kloc + j][hdl]);
    const int hd = hd0 + hdl;
    const int h = hd >> 7;
    const int ntd = (hd & 127) >> 5;
    const int l31 = hd & 31;
    size_t pos = ((((size_t)(h * 32 + by) * 4 + ntd) * 2 + c) * 2 + hi) * 32 + l31;
    *(short8*)(&Vfrag[pos * 8]) = v;
}

// ---------------- Flash attention (cross-tile software pipeline) ----------------
// KVBLK=32; K double-buffered, V TRIPLE-buffered (40KB LDS). Body t computes
// sa_cur = QK(t) and SM(sa_prev)+PV(t-1) ADJACENTLY (no data dependence -> compiler
// interleaves QK ds_reads/MFMAs with softmax VALU and PV MFMAs; T15 mechanism).
// Buffer safety: QK(t) reads K[t&1], stage writes K[(t+1)&1] (disjoint); PV(t-1)
// reads V[(t-1)%3], stage writes V[(t+1)%3] (disjoint mod 3); every staged buffer
// crosses a __syncthreads before any wave reads it (round-11 rule).
// Softmax: fixed shift, v_cvt_pk_bf16_f32 pack, permlane32_swap, scalar psum.
__global__ __launch_bounds__(256, 3) void attn(const float* __restrict__ Q,
                                               const unsigned short* __restrict__ Kbf,
                                               const unsigned short* __restrict__ Vfrag,
                                               float* __restrict__ O) {
    __shared__ __align__(16) unsigned short Ks[2][32 * 128];   // [key][d], src-swizzled
    __shared__ __align__(16) unsigned short Vs[3][32 * 128];   // fragment-order, linear
    const int tid = threadIdx.x;
    const int lane = tid & 63;
    const int wave = tid >> 6;
    const int l31 = lane & 31;
    const int hi = lane >> 5;
    const int flat = blockIdx.x + gridDim.x * blockIdx.y;  // gridDim.x = 32
    const int wid = (flat & 7) * 96 + (flat >> 3);          // bijective: 768 = 8*96
    const int h = wid >> 5;
    const int q0 = (wid & 31) * 128 + wave * 32;
    const float qscale = 0.08838834764831843f * 1.44269504088896340736f;  // D^-0.5 * log2(e)
    const float SHIFT = 32.0f;
    const int NT = LK / 32;  // 32 kv-tiles

    // hoist Q B-fragments: lane holds Q[q0+l31][m*16 + hi*8 + j], m=0..7
    short8 qf[8];
#pragma unroll
    for (int m = 0; m < 8; ++m) {
        const float* qp = &Q[(q0 + l31) * HID + h * HD + m * 16 + hi * 8];
        float4 lo = *(const float4*)(qp);
        float4 hif = *(const float4*)(qp + 4);
        short8 v;
        v[0] = (short)f2bf(lo.x * qscale);
        v[1] = (short)f2bf(lo.y * qscale);
        v[2] = (short)f2bf(lo.z * qscale);
        v[3] = (short)f2bf(lo.w * qscale);
        v[4] = (short)f2bf(hif.x * qscale);
        v[5] = (short)f2bf(hif.y * qscale);
        v[6] = (short)f2bf(hif.z * qscale);
        v[7] = (short)f2bf(hif.w * qscale);
        qf[m] = v;
    }

    floatx16 accO[4];
#pragma unroll
    for (int i = 0; i < 4; ++i)
#pragma unroll
        for (int r = 0; r < 16; ++r) accO[i][r] = 0.f;
    float psum = 0.f;

    auto stageK = [&](int b, int kt) {
        for (int i = 0; i < 2; ++i) {
            int slot = i * 256 + tid;             // 512 slots = 32 rows x 16 blocks
            int r = slot >> 4, bb = slot & 15;
            int g = bb ^ (r & 15);
            gload16(&Kbf[(kt * 32 + r) * HID + h * HD + g * 8],
                    &Ks[b][(i * 256 + wave * 64) * 8]);
        }
    };
    auto stageV = [&](int b, int kt) {
        const unsigned short* src = Vfrag + ((size_t)(h * 32 + kt) << 12);  // 8KB tile
        for (int i = 0; i < 2; ++i) {
            int slot = i * 256 + tid;
            gload16(&src[slot * 8], &Vs[b][(i * 256 + wave * 64) * 8]);
        }
    };

    auto qkt = [&](int b) {
        floatx16 sa;
#pragma unroll
        for (int r = 0; r < 16; ++r) sa[r] = -SHIFT;
#pragma unroll
        for (int m = 0; m < 8; ++m) {
            int c = m * 2 + hi;
            int slot = l31 * 16 + (c ^ (l31 & 15));
            short8 kf = *(const short8*)(&Ks[b][slot * 8]);
            sa = __builtin_amdgcn_mfma_f32_32x32x16_bf16(kf, qf[m], sa, 0, 0, 0);
        }
        return sa;
    };

    // softmax + PV for one S-block (keys of tile read from Vs[vb])
    auto smpv = [&](floatx16 sa, int vb) {
        unsigned d0, d1, d2, d3, d4, d5, d6, d7;
        {
            float e0, e1, ps = 0.f;
            e0 = exp2f(sa[0]);  e1 = exp2f(sa[1]);  ps += e0 + e1; d0 = cvtpk(e0, e1);
            e0 = exp2f(sa[2]);  e1 = exp2f(sa[3]);  ps += e0 + e1; d1 = cvtpk(e0, e1);
            e0 = exp2f(sa[4]);  e1 = exp2f(sa[5]);  ps += e0 + e1; d2 = cvtpk(e0, e1);
            e0 = exp2f(sa[6]);  e1 = exp2f(sa[7]);  ps += e0 + e1; d3 = cvtpk(e0, e1);
            e0 = exp2f(sa[8]);  e1 = exp2f(sa[9]);  ps += e0 + e1; d4 = cvtpk(e0, e1);
            e0 = exp2f(sa[10]); e1 = exp2f(sa[11]); ps += e0 + e1; d5 = cvtpk(e0, e1);
            e0 = exp2f(sa[12]); e1 = exp2f(sa[13]); ps += e0 + e1; d6 = cvtpk(e0, e1);
            e0 = exp2f(sa[14]); e1 = exp2f(sa[15]); ps += e0 + e1; d7 = cvtpk(e0, e1);
            psum += ps;
        }
        asm volatile("v_permlane32_swap_b32 %0, %1" : "+v"(d0), "+v"(d2));
        asm volatile("v_permlane32_swap_b32 %0, %1" : "+v"(d1), "+v"(d3));
        asm volatile("v_permlane32_swap_b32 %0, %1" : "+v"(d4), "+v"(d6));
        asm volatile("v_permlane32_swap_b32 %0, %1" : "+v"(d5), "+v"(d7));
        union { unsigned u[4]; short8 s; } p0, p1;
        p0.u[0] = d0; p0.u[1] = d1; p0.u[2] = d2; p0.u[3] = d3;  // keys 0..15
        p1.u[0] = d4; p1.u[1] = d5; p1.u[2] = d6; p1.u[3] = d7;  // keys 16..31
#pragma unroll
        for (int ntd = 0; ntd < 4; ++ntd) {
            int s0 = ((ntd * 2 + 0) * 2 + hi) * 32 + l31;
            int s1 = ((ntd * 2 + 1) * 2 + hi) * 32 + l31;
            short8 vf0 = *(const short8*)(&Vs[vb][s0 * 8]);
            short8 vf1 = *(const short8*)(&Vs[vb][s1 * 8]);
            accO[ntd] = __builtin_amdgcn_mfma_f32_32x32x16_bf16(p0.s, vf0, accO[ntd], 0, 0, 0);
            accO[ntd] = __builtin_amdgcn_mfma_f32_32x32x16_bf16(p1.s, vf1, accO[ntd], 0, 0, 0);
        }
    };

    // ---- pipelined main loop ----
    stageK(0, 0);
    stageV(0, 0);
    __syncthreads();                       // tile 0 visible to all waves
    stageK(1, 1);
    stageV(1, 1);
    floatx16 sa_prev = qkt(0);             // reads Ks[0]
    __syncthreads();                       // tile 1 visible

    for (int t = 1; t < NT; ++t) {
        if (t < NT - 1) {
            stageK((t + 1) & 1, t + 1);    // disjoint from Ks[t&1] being read
            stageV((t + 1) % 3, t + 1);    // disjoint from Vs[(t-1)%3] being read
        }
        floatx16 sa_cur = qkt(t & 1);      // independent of smpv below -> ILP overlap
        smpv(sa_prev, (t - 1) % 3);
        sa_prev = sa_cur;
        __syncthreads();
    }
    smpv(sa_prev, (NT - 1) % 3);

    // epilogue: psum covers half the keys; partner (lane^32) has the rest
    float s = psum + __shfl_xor(psum, 32);
    float rinv = 1.0f / s;  // valid for q = l31
    float ri[16];
#pragma unroll
    for (int r = 0; r < 16; ++r) {
        int row = (r & 3) + 8 * (r >> 2) + 4 * hi;
        ri[r] = __shfl(rinv, row);
    }
#pragma unroll
    for (int ntd = 0; ntd < 4; ++ntd)
#pragma unroll
        for (int r = 0; r < 16; ++r) {
            int row = (r & 3) + 8 * (r >> 2) + 4 * hi;
            O[(q0 + row) * HID + h * HD + ntd * 32 + l31] = accO[ntd][r] * ri[r];
        }
}

extern "C" void kernel_launch(void* const* d_in, const int* in_sizes, int n_in,
                              void* d_out, int out_size, void* d_ws, size_t ws_size,
                              hipStream_t stream) {
    const float* Q      = (const float*)d_in[0];
    const float* latent = (const float*)d_in[1];
    const float* freqs  = (const float*)d_in[2];
    const float* Wk     = (const float*)d_in[3];
    const float* Wv     = (const float*)d_in[4];
    const float* rmsw   = (const float*)d_in[5];
    float* out = (float*)d_out;
    char* ws = (char*)d_ws;

    // ws layout (62,914,560 bytes; Wv reuses Wk's slot — stream order serializes)
    unsigned short* latent_bf = (unsigned short*)(ws);               //  6,291,456
    unsigned short* Wbf       = (unsigned short*)(ws + 6291456);     // 18,874,368 (Wk, then Wv)
    float*          raw0      = (float*)(ws + 25165824);             // 12,582,912 split-K partial 0
    float*          raw1      = (float*)(ws + 37748736);             // 12,582,912 split-K partial 1
    unsigned short* Kbf       = (unsigned short*)(ws + 50331648);    //  6,291,456
    unsigned short* Vfrag     = (unsigned short*)(ws + 56623104);    //  6,291,456

    f32_to_bf16<<<2048, 256, 0, stream>>>(latent, latent_bf, (LK * HID) / 4);
    f32_to_bf16<<<2048, 256, 0, stream>>>(Wk, Wbf, (HID * HID) / 4);

    gemm_proj<<<dim3(16, 24, 2), 256, 0, stream>>>(latent_bf, Wbf, raw0, LK, HID, HID);
    rmsnorm_rope<<<(LK * NH) / 2, 256, 0, stream>>>(raw0, raw1, freqs, rmsw, Kbf);

    f32_to_bf16<<<2048, 256, 0, stream>>>(Wv, Wbf, (HID * HID) / 4);
    gemm_proj<<<dim3(16, 24, 2), 256, 0, stream>>>(latent_bf, Wbf, raw0, LK, HID, HID);
    transpose_v<<<dim3(HID / 64, LK / 32), 256, 0, stream>>>(raw0, raw1, Vfrag);

    attn<<<dim3(LQ / 128, NH), 256, 0, stream>>>(Q, Kbf, Vfrag, out);
}

// Round 14
// 172.832 us; speedup vs baseline: 1.0170x; 1.0170x over previous
//
#include <hip/hip_runtime.h>
#include <hip/hip_bf16.h>

typedef __attribute__((ext_vector_type(8))) short short8;
typedef float floatx4 __attribute__((ext_vector_type(4)));
typedef float floatx16 __attribute__((ext_vector_type(16)));

#define LQ 4096
#define LK 1024
#define NH 24
#define HD 128
#define HID 3072

__device__ __forceinline__ unsigned short f2bf(float f) {
    __hip_bfloat16 h = __float2bfloat16(f);
    union { __hip_bfloat16 b; unsigned short u; } c; c.b = h;
    return c.u;
}

// pack two f32 -> packed 2x bf16 in one instr (RNE)
__device__ __forceinline__ unsigned cvtpk(float a, float b) {
    unsigned r;
    asm("v_cvt_pk_bf16_f32 %0, %1, %2" : "=v"(r) : "v"(a), "v"(b));
    return r;
}

// async global->LDS, 16B per lane. LDS dest must be wave-uniform base (HW adds lane*16).
__device__ __forceinline__ void gload16(const void* g, void* l) {
    __builtin_amdgcn_global_load_lds(
        (const __attribute__((address_space(1))) void*)g,
        (__attribute__((address_space(3))) void*)l,
        16, 0, 0);
}

// ---------------- f32 -> bf16 convert ----------------
__global__ void f32_to_bf16(const float* __restrict__ in, unsigned short* __restrict__ out, int n4) {
    int i = blockIdx.x * blockDim.x + threadIdx.x;
    int stride = gridDim.x * blockDim.x;
    for (; i < n4; i += stride) {
        float4 v = ((const float4*)in)[i];
        ushort4 o;
        o.x = f2bf(v.x); o.y = f2bf(v.y); o.z = f2bf(v.z); o.w = f2bf(v.w);
        ((ushort4*)out)[i] = o;
    }
}

// ---------------- bf16 GEMM, split-K=2 (proven round-8 structure) ----------------
__global__ __launch_bounds__(256) void gemm_proj(const unsigned short* __restrict__ A,
                                                 const unsigned short* __restrict__ Bw,
                                                 float* __restrict__ C,
                                                 int M, int N, int K) {
    __shared__ __align__(16) unsigned short As[2][64 * 64];
    __shared__ __align__(16) unsigned short Bs[2][128 * 64];
    const int tid = threadIdx.x;
    const int lane = tid & 63;
    const int wave = tid >> 6;
    const int wm = wave >> 1, wn = wave & 1;
    const int flat = blockIdx.x + gridDim.x * blockIdx.y;  // 0..383 within z-slice
    const int wid = (flat & 7) * 48 + (flat >> 3);         // XCD-contiguous
    const int bm0 = (wid & 15) * 64;
    const int bn0 = (wid >> 4) * 128;
    const int kbeg = blockIdx.z * (K >> 1);
    const int kend = kbeg + (K >> 1);
    float* Cz = C + (size_t)blockIdx.z * M * N;
    const int lr = lane & 15;
    const int lg = lane >> 4;

    floatx4 acc[2][4];
    for (int i = 0; i < 2; ++i)
        for (int j = 0; j < 4; ++j)
            acc[i][j] = (floatx4){0.f, 0.f, 0.f, 0.f};

    auto stage = [&](int b, int k0) {
        for (int p = 0; p < 2; ++p) {
            int slot = p * 256 + tid;
            int r = slot >> 3, cb = slot & 7;
            int g = cb ^ (r & 7);
            gload16(&A[(bm0 + r) * K + k0 + g * 8], &As[b][(p * 256 + wave * 64) * 8]);
        }
        for (int p = 0; p < 4; ++p) {
            int slot = p * 256 + tid;
            int r = slot >> 3, cb = slot & 7;
            int g = cb ^ (r & 7);
            gload16(&Bw[(bn0 + r) * K + k0 + g * 8], &Bs[b][(p * 256 + wave * 64) * 8]);
        }
    };

    auto compute = [&](int b) {
        for (int ks = 0; ks < 2; ++ks) {
            short8 af[2], bfr[4];
            for (int mt = 0; mt < 2; ++mt) {
                int m = wm * 32 + mt * 16 + lr;
                int sc = (ks * 4 + lg) ^ (m & 7);
                af[mt] = *(const short8*)(&As[b][m * 64 + sc * 8]);
            }
            for (int nt = 0; nt < 4; ++nt) {
                int n = wn * 64 + nt * 16 + lr;
                int sc = (ks * 4 + lg) ^ (n & 7);
                bfr[nt] = *(const short8*)(&Bs[b][n * 64 + sc * 8]);
            }
            __builtin_amdgcn_s_setprio(1);
            for (int mt = 0; mt < 2; ++mt)
                for (int nt = 0; nt < 4; ++nt)
                    acc[mt][nt] = __builtin_amdgcn_mfma_f32_16x16x32_bf16(af[mt], bfr[nt], acc[mt][nt], 0, 0, 0);
            __builtin_amdgcn_s_setprio(0);
        }
    };

    stage(0, kbeg);
    __syncthreads();
    int buf = 0;
    for (int k0 = kbeg; k0 < kend - 64; k0 += 64) {
        stage(buf ^ 1, k0 + 64);
        compute(buf);
        __syncthreads();
        buf ^= 1;
    }
    compute(buf);

    for (int mt = 0; mt < 2; ++mt)
        for (int nt = 0; nt < 4; ++nt)
            for (int rg = 0; rg < 4; ++rg) {
                int m = bm0 + wm * 32 + mt * 16 + lg * 4 + rg;
                int n = bn0 + wn * 64 + nt * 16 + lr;
                Cz[m * N + n] = acc[mt][nt][rg];
            }
}

// ---------------- RMSNorm + RoPE on K (reads two split-K partials) ----------------
__global__ __launch_bounds__(256) void rmsnorm_rope(const float* __restrict__ r0,
                                                    const float* __restrict__ r1,
                                                    const float* __restrict__ freqs,
                                                    const float* __restrict__ w,
                                                    unsigned short* __restrict__ Kbf) {
    int row = blockIdx.x * 2 + (threadIdx.x >> 7);  // l*NH + h
    int l = row / NH, h = row % NH;
    int d = threadIdx.x & 127;
    int idx = l * HID + h * HD + d;
    float x = r0[idx] + r1[idx];
    float ss = x * x;
    for (int off = 32; off; off >>= 1) ss += __shfl_xor(ss, off);
    __shared__ float red[4];
    int wv = threadIdx.x >> 6;
    if ((threadIdx.x & 63) == 0) red[wv] = ss;
    __syncthreads();
    int base = (threadIdx.x >> 7) * 2;
    float tot = red[base] + red[base + 1];
    float rsn = rsqrtf(tot * (1.0f / 128.0f) + 1e-6f);
    float xn = x * rsn * w[d];
    float f = freqs[l * (HD / 2) + (d >> 1)];
    float s = __sinf(f), c = __cosf(f);   // freqs in [0,1): no range reduction needed
    float partner = __shfl_xor(xn, 1);
    float o = (d & 1) ? (partner * s + xn * c) : (xn * c - partner * s);
    Kbf[idx] = f2bf(o);
}

// ---------------- V transpose -> FRAGMENT-ORDER global layout (32-key tiles) ----
// Vfrag[h][kt32][ntd][c][hi][l31]: 16B vector = bf16 V[kt32*32 + c*16 + hi*8 + j]
// [hd = h*128 + ntd*32 + l31]. One head+ktile = contiguous 8KB -> attn stages it
// with 2 linear gload16; reads hit 32 consecutive slots (conflict-free).
__global__ __launch_bounds__(256) void transpose_v(const float* __restrict__ r0,
                                                   const float* __restrict__ r1,
                                                   unsigned short* __restrict__ Vfrag) {
    __shared__ float tile[32][65];
    const int bx = blockIdx.x;          // hd0/64: 0..47
    const int by = blockIdx.y;          // kt32: 0..31
    const int hd0 = bx * 64, l0 = by * 32;
    const int tx = threadIdx.x & 63;
    const int tg8 = threadIdx.x >> 6;   // 0..3
    for (int i = 0; i < 8; ++i) {
        int r = tg8 * 8 + i;
        int idx = (l0 + r) * HID + hd0 + tx;
        tile[r][tx] = r0[idx] + r1[idx];
    }
    __syncthreads();
    const int tg = threadIdx.x >> 6;    // 0..3
    const int c = tg >> 1, hi = tg & 1;
    const int hdl = threadIdx.x & 63;
    const int kloc = c * 16 + hi * 8;
    short8 v;
    for (int j = 0; j < 8; ++j)
        v[j] = (short)f2bf(tile[kloc + j][hdl]);
    const int hd = hd0 + hdl;
    const int h = hd >> 7;
    const int ntd = (hd & 127) >> 5;
    const int l31 = hd & 31;
    size_t pos = ((((size_t)(h * 32 + by) * 4 + ntd) * 2 + c) * 2 + hi) * 32 + l31;
    *(short8*)(&Vfrag[pos * 8]) = v;
}

// ---------------- Flash attention (round-12 skeleton + cvtpk + setprio) ----------
// KVBLK=32, K and V double-buffered (32KB LDS), stage(t+1) -> compute(t) ->
// __syncthreads(). Swapped QK^T (mfma(K,Q), 32x32x16), in-register softmax
// (fixed shift, v_cvt_pk_bf16_f32, permlane32_swap), scalar psum. Fragment-order
// V (0 bank conflicts). s_setprio(1) around MFMA clusters (T5: scheduler favors
// the MFMA-issuing wave while co-resident blocks stage/softmax).
__global__ __launch_bounds__(256, 3) void attn(const float* __restrict__ Q,
                                               const unsigned short* __restrict__ Kbf,
                                               const unsigned short* __restrict__ Vfrag,
                                               float* __restrict__ O) {
    __shared__ __align__(16) unsigned short Ks[2][32 * 128];   // [key][d], src-swizzled
    __shared__ __align__(16) unsigned short Vs[2][32 * 128];   // fragment-order, linear
    const int tid = threadIdx.x;
    const int lane = tid & 63;
    const int wave = tid >> 6;
    const int l31 = lane & 31;
    const int hi = lane >> 5;
    const int flat = blockIdx.x + gridDim.x * blockIdx.y;  // gridDim.x = 32
    const int wid = (flat & 7) * 96 + (flat >> 3);          // bijective: 768 = 8*96
    const int h = wid >> 5;
    const int q0 = (wid & 31) * 128 + wave * 32;
    const float qscale = 0.08838834764831843f * 1.44269504088896340736f;  // D^-0.5 * log2(e)
    const float SHIFT = 32.0f;
    const int NT = LK / 32;  // 32 kv-tiles

    // hoist Q B-fragments: lane holds Q[q0+l31][m*16 + hi*8 + j], m=0..7
    short8 qf[8];
#pragma unroll
    for (int m = 0; m < 8; ++m) {
        const float* qp = &Q[(q0 + l31) * HID + h * HD + m * 16 + hi * 8];
        float4 lo = *(const float4*)(qp);
        float4 hif = *(const float4*)(qp + 4);
        short8 v;
        v[0] = (short)f2bf(lo.x * qscale);
        v[1] = (short)f2bf(lo.y * qscale);
        v[2] = (short)f2bf(lo.z * qscale);
        v[3] = (short)f2bf(lo.w * qscale);
        v[4] = (short)f2bf(hif.x * qscale);
        v[5] = (short)f2bf(hif.y * qscale);
        v[6] = (short)f2bf(hif.z * qscale);
        v[7] = (short)f2bf(hif.w * qscale);
        qf[m] = v;
    }

    floatx16 accO[4];
#pragma unroll
    for (int i = 0; i < 4; ++i)
#pragma unroll
        for (int r = 0; r < 16; ++r) accO[i][r] = 0.f;
    float psum = 0.f;

    auto stageK = [&](int b, int kt) {
        for (int i = 0; i < 2; ++i) {
            int slot = i * 256 + tid;             // 512 slots = 32 rows x 16 blocks
            int r = slot >> 4, bb = slot & 15;
            int g = bb ^ (r & 15);
            gload16(&Kbf[(kt * 32 + r) * HID + h * HD + g * 8],
                    &Ks[b][(i * 256 + wave * 64) * 8]);
        }
    };
    auto stageV = [&](int b, int kt) {
        const unsigned short* src = Vfrag + ((size_t)(h * 32 + kt) << 12);  // 8KB tile
        for (int i = 0; i < 2; ++i) {
            int slot = i * 256 + tid;
            gload16(&src[slot * 8], &Vs[b][(i * 256 + wave * 64) * 8]);
        }
    };

    auto compute = [&](int b) {
        floatx16 sa;
#pragma unroll
        for (int r = 0; r < 16; ++r) sa[r] = -SHIFT;
        // QK^T: A = K[key=l31][k=m*16+hi*8+j] (swizzled read), B = Q fragment
        __builtin_amdgcn_s_setprio(1);
#pragma unroll
        for (int m = 0; m < 8; ++m) {
            int c = m * 2 + hi;
            int slot = l31 * 16 + (c ^ (l31 & 15));
            short8 kf = *(const short8*)(&Ks[b][slot * 8]);
            sa = __builtin_amdgcn_mfma_f32_32x32x16_bf16(kf, qf[m], sa, 0, 0, 0);
        }
        __builtin_amdgcn_s_setprio(0);
        // softmax: P = exp2(S - SHIFT); cvt_pk pack; permlane32_swap -> A-fragments
        unsigned d0, d1, d2, d3, d4, d5, d6, d7;
        {
            float e0, e1, ps = 0.f;
            e0 = exp2f(sa[0]);  e1 = exp2f(sa[1]);  ps += e0 + e1; d0 = cvtpk(e0, e1);
            e0 = exp2f(sa[2]);  e1 = exp2f(sa[3]);  ps += e0 + e1; d1 = cvtpk(e0, e1);
            e0 = exp2f(sa[4]);  e1 = exp2f(sa[5]);  ps += e0 + e1; d2 = cvtpk(e0, e1);
            e0 = exp2f(sa[6]);  e1 = exp2f(sa[7]);  ps += e0 + e1; d3 = cvtpk(e0, e1);
            e0 = exp2f(sa[8]);  e1 = exp2f(sa[9]);  ps += e0 + e1; d4 = cvtpk(e0, e1);
            e0 = exp2f(sa[10]); e1 = exp2f(sa[11]); ps += e0 + e1; d5 = cvtpk(e0, e1);
            e0 = exp2f(sa[12]); e1 = exp2f(sa[13]); ps += e0 + e1; d6 = cvtpk(e0, e1);
            e0 = exp2f(sa[14]); e1 = exp2f(sa[15]); ps += e0 + e1; d7 = cvtpk(e0, e1);
            psum += ps;
        }
        asm volatile("v_permlane32_swap_b32 %0, %1" : "+v"(d0), "+v"(d2));
        asm volatile("v_permlane32_swap_b32 %0, %1" : "+v"(d1), "+v"(d3));
        asm volatile("v_permlane32_swap_b32 %0, %1" : "+v"(d4), "+v"(d6));
        asm volatile("v_permlane32_swap_b32 %0, %1" : "+v"(d5), "+v"(d7));
        union { unsigned u[4]; short8 s; } p0, p1;
        p0.u[0] = d0; p0.u[1] = d1; p0.u[2] = d2; p0.u[3] = d3;  // keys 0..15
        p1.u[0] = d4; p1.u[1] = d5; p1.u[2] = d6; p1.u[3] = d7;  // keys 16..31
        // O += P V: B-fragment slot = ((ntd*2 + c)*2 + hi)*32 + l31 — conflict-free
        __builtin_amdgcn_s_setprio(1);
#pragma unroll
        for (int ntd = 0; ntd < 4; ++ntd) {
            int s0 = ((ntd * 2 + 0) * 2 + hi) * 32 + l31;
            int s1 = ((ntd * 2 + 1) * 2 + hi) * 32 + l31;
            short8 vf0 = *(const short8*)(&Vs[b][s0 * 8]);
            short8 vf1 = *(const short8*)(&Vs[b][s1 * 8]);
            accO[ntd] = __builtin_amdgcn_mfma_f32_32x32x16_bf16(p0.s, vf0, accO[ntd], 0, 0, 0);
            accO[ntd] = __builtin_amdgcn_mfma_f32_32x32x16_bf16(p1.s, vf1, accO[ntd], 0, 0, 0);
        }
        __builtin_amdgcn_s_setprio(0);
    };

    stageK(0, 0);
    stageV(0, 0);
    __syncthreads();
    int buf = 0;
    for (int t = 0; t < NT - 1; ++t) {
        stageK(buf ^ 1, t + 1);
        stageV(buf ^ 1, t + 1);
        compute(buf);
        __syncthreads();
        buf ^= 1;
    }
    compute(buf);

    // epilogue: psum covers half the keys; partner (lane^32) has the rest
    float s = psum + __shfl_xor(psum, 32);
    float rinv = 1.0f / s;  // valid for q = l31
    float ri[16];
#pragma unroll
    for (int r = 0; r < 16; ++r) {
        int row = (r & 3) + 8 * (r >> 2) + 4 * hi;
        ri[r] = __shfl(rinv, row);
    }
#pragma unroll
    for (int ntd = 0; ntd < 4; ++ntd)
#pragma unroll
        for (int r = 0; r < 16; ++r) {
            int row = (r & 3) + 8 * (r >> 2) + 4 * hi;
            O[(q0 + row) * HID + h * HD + ntd * 32 + l31] = accO[ntd][r] * ri[r];
        }
}

extern "C" void kernel_launch(void* const* d_in, const int* in_sizes, int n_in,
                              void* d_out, int out_size, void* d_ws, size_t ws_size,
                              hipStream_t stream) {
    const float* Q      = (const float*)d_in[0];
    const float* latent = (const float*)d_in[1];
    const float* freqs  = (const float*)d_in[2];
    const float* Wk     = (const float*)d_in[3];
    const float* Wv     = (const float*)d_in[4];
    const float* rmsw   = (const float*)d_in[5];
    float* out = (float*)d_out;
    char* ws = (char*)d_ws;

    // ws layout (62,914,560 bytes; Wv reuses Wk's slot — stream order serializes)
    unsigned short* latent_bf = (unsigned short*)(ws);               //  6,291,456
    unsigned short* Wbf       = (unsigned short*)(ws + 6291456);     // 18,874,368 (Wk, then Wv)
    float*          raw0      = (float*)(ws + 25165824);             // 12,582,912 split-K partial 0
    float*          raw1      = (float*)(ws + 37748736);             // 12,582,912 split-K partial 1
    unsigned short* Kbf       = (unsigned short*)(ws + 50331648);    //  6,291,456
    unsigned short* Vfrag     = (unsigned short*)(ws + 56623104);    //  6,291,456

    f32_to_bf16<<<2048, 256, 0, stream>>>(latent, latent_bf, (LK * HID) / 4);
    f32_to_bf16<<<2048, 256, 0, stream>>>(Wk, Wbf, (HID * HID) / 4);

    gemm_proj<<<dim3(16, 24, 2), 256, 0, stream>>>(latent_bf, Wbf, raw0, LK, HID, HID);
    rmsnorm_rope<<<(LK * NH) / 2, 256, 0, stream>>>(raw0, raw1, freqs, rmsw, Kbf);

    f32_to_bf16<<<2048, 256, 0, stream>>>(Wv, Wbf, (HID * HID) / 4);
    gemm_proj<<<dim3(16, 24, 2), 256, 0, stream>>>(latent_bf, Wbf, raw0, LK, HID, HID);
    transpose_v<<<dim3(HID / 64, LK / 32), 256, 0, stream>>>(raw0, raw1, Vfrag);

    attn<<<dim3(LQ / 128, NH), 256, 0, stream>>>(Q, Kbf, Vfrag, out);
}

// Round 15
// 165.107 us; speedup vs baseline: 1.0645x; 1.0468x over previous
//
#include <hip/hip_runtime.h>
#include <hip/hip_bf16.h>

typedef __attribute__((ext_vector_type(8))) short short8;
typedef float floatx4 __attribute__((ext_vector_type(4)));
typedef float floatx16 __attribute__((ext_vector_type(16)));

#define LQ 4096
#define LK 1024
#define NH 24
#define HD 128
#define HID 3072

__device__ __forceinline__ unsigned short f2bf(float f) {
    __hip_bfloat16 h = __float2bfloat16(f);
    union { __hip_bfloat16 b; unsigned short u; } c; c.b = h;
    return c.u;
}

// pack two f32 -> packed 2x bf16 in one instr (RNE)
__device__ __forceinline__ unsigned cvtpk(float a, float b) {
    unsigned r;
    asm("v_cvt_pk_bf16_f32 %0, %1, %2" : "=v"(r) : "v"(a), "v"(b));
    return r;
}

// guaranteed single-instruction 2^x
__device__ __forceinline__ float fexp2(float x) {
    float r;
    asm("v_exp_f32 %0, %1" : "=v"(r) : "v"(x));
    return r;
}

// async global->LDS, 16B per lane. LDS dest must be wave-uniform base (HW adds lane*16).
__device__ __forceinline__ void gload16(const void* g, void* l) {
    __builtin_amdgcn_global_load_lds(
        (const __attribute__((address_space(1))) void*)g,
        (__attribute__((address_space(3))) void*)l,
        16, 0, 0);
}

// ---------------- f32 -> bf16 convert ----------------
__global__ void f32_to_bf16(const float* __restrict__ in, unsigned short* __restrict__ out, int n4) {
    int i = blockIdx.x * blockDim.x + threadIdx.x;
    int stride = gridDim.x * blockDim.x;
    for (; i < n4; i += stride) {
        float4 v = ((const float4*)in)[i];
        ushort4 o;
        o.x = f2bf(v.x); o.y = f2bf(v.y); o.z = f2bf(v.z); o.w = f2bf(v.w);
        ((ushort4*)out)[i] = o;
    }
}

// ---------------- bf16 GEMM, split-K=2 (proven round-8 structure) ----------------
__global__ __launch_bounds__(256) void gemm_proj(const unsigned short* __restrict__ A,
                                                 const unsigned short* __restrict__ Bw,
                                                 float* __restrict__ C,
                                                 int M, int N, int K) {
    __shared__ __align__(16) unsigned short As[2][64 * 64];
    __shared__ __align__(16) unsigned short Bs[2][128 * 64];
    const int tid = threadIdx.x;
    const int lane = tid & 63;
    const int wave = tid >> 6;
    const int wm = wave >> 1, wn = wave & 1;
    const int flat = blockIdx.x + gridDim.x * blockIdx.y;  // 0..383 within z-slice
    const int wid = (flat & 7) * 48 + (flat >> 3);         // XCD-contiguous
    const int bm0 = (wid & 15) * 64;
    const int bn0 = (wid >> 4) * 128;
    const int kbeg = blockIdx.z * (K >> 1);
    const int kend = kbeg + (K >> 1);
    float* Cz = C + (size_t)blockIdx.z * M * N;
    const int lr = lane & 15;
    const int lg = lane >> 4;

    floatx4 acc[2][4];
    for (int i = 0; i < 2; ++i)
        for (int j = 0; j < 4; ++j)
            acc[i][j] = (floatx4){0.f, 0.f, 0.f, 0.f};

    auto stage = [&](int b, int k0) {
        for (int p = 0; p < 2; ++p) {
            int slot = p * 256 + tid;
            int r = slot >> 3, cb = slot & 7;
            int g = cb ^ (r & 7);
            gload16(&A[(bm0 + r) * K + k0 + g * 8], &As[b][(p * 256 + wave * 64) * 8]);
        }
        for (int p = 0; p < 4; ++p) {
            int slot = p * 256 + tid;
            int r = slot >> 3, cb = slot & 7;
            int g = cb ^ (r & 7);
            gload16(&Bw[(bn0 + r) * K + k0 + g * 8], &Bs[b][(p * 256 + wave * 64) * 8]);
        }
    };

    auto compute = [&](int b) {
        for (int ks = 0; ks < 2; ++ks) {
            short8 af[2], bfr[4];
            for (int mt = 0; mt < 2; ++mt) {
                int m = wm * 32 + mt * 16 + lr;
                int sc = (ks * 4 + lg) ^ (m & 7);
                af[mt] = *(const short8*)(&As[b][m * 64 + sc * 8]);
            }
            for (int nt = 0; nt < 4; ++nt) {
                int n = wn * 64 + nt * 16 + lr;
                int sc = (ks * 4 + lg) ^ (n & 7);
                bfr[nt] = *(const short8*)(&Bs[b][n * 64 + sc * 8]);
            }
            __builtin_amdgcn_s_setprio(1);
            for (int mt = 0; mt < 2; ++mt)
                for (int nt = 0; nt < 4; ++nt)
                    acc[mt][nt] = __builtin_amdgcn_mfma_f32_16x16x32_bf16(af[mt], bfr[nt], acc[mt][nt], 0, 0, 0);
            __builtin_amdgcn_s_setprio(0);
        }
    };

    stage(0, kbeg);
    __syncthreads();
    int buf = 0;
    for (int k0 = kbeg; k0 < kend - 64; k0 += 64) {
        stage(buf ^ 1, k0 + 64);
        compute(buf);
        __syncthreads();
        buf ^= 1;
    }
    compute(buf);

    for (int mt = 0; mt < 2; ++mt)
        for (int nt = 0; nt < 4; ++nt)
            for (int rg = 0; rg < 4; ++rg) {
                int m = bm0 + wm * 32 + mt * 16 + lg * 4 + rg;
                int n = bn0 + wn * 64 + nt * 16 + lr;
                Cz[m * N + n] = acc[mt][nt][rg];
            }
}

// ---------------- RMSNorm + RoPE on K (reads two split-K partials) ----------------
__global__ __launch_bounds__(256) void rmsnorm_rope(const float* __restrict__ r0,
                                                    const float* __restrict__ r1,
                                                    const float* __restrict__ freqs,
                                                    const float* __restrict__ w,
                                                    unsigned short* __restrict__ Kbf) {
    int row = blockIdx.x * 2 + (threadIdx.x >> 7);  // l*NH + h
    int l = row / NH, h = row % NH;
    int d = threadIdx.x & 127;
    int idx = l * HID + h * HD + d;
    float x = r0[idx] + r1[idx];
    float ss = x * x;
    for (int off = 32; off; off >>= 1) ss += __shfl_xor(ss, off);
    __shared__ float red[4];
    int wv = threadIdx.x >> 6;
    if ((threadIdx.x & 63) == 0) red[wv] = ss;
    __syncthreads();
    int base = (threadIdx.x >> 7) * 2;
    float tot = red[base] + red[base + 1];
    float rsn = rsqrtf(tot * (1.0f / 128.0f) + 1e-6f);
    float xn = x * rsn * w[d];
    float f = freqs[l * (HD / 2) + (d >> 1)];
    float s = __sinf(f), c = __cosf(f);   // freqs in [0,1): no range reduction needed
    float partner = __shfl_xor(xn, 1);
    float o = (d & 1) ? (partner * s + xn * c) : (xn * c - partner * s);
    Kbf[idx] = f2bf(o);
}

// ---------------- V transpose -> FRAGMENT-ORDER global layout (32-key tiles) ----
// Vfrag[h][kt32][ntd][c][hi][l31]: 16B vector = bf16 V[kt32*32 + c*16 + hi*8 + j]
// [hd = h*128 + ntd*32 + l31]. One head+ktile = contiguous 8KB -> attn stages it
// with 2 linear gload16; reads hit 32 consecutive slots (conflict-free).
__global__ __launch_bounds__(256) void transpose_v(const float* __restrict__ r0,
                                                   const float* __restrict__ r1,
                                                   unsigned short* __restrict__ Vfrag) {
    __shared__ float tile[32][65];
    const int bx = blockIdx.x;          // hd0/64: 0..47
    const int by = blockIdx.y;          // kt32: 0..31
    const int hd0 = bx * 64, l0 = by * 32;
    const int tx = threadIdx.x & 63;
    const int tg8 = threadIdx.x >> 6;   // 0..3
    for (int i = 0; i < 8; ++i) {
        int r = tg8 * 8 + i;
        int idx = (l0 + r) * HID + hd0 + tx;
        tile[r][tx] = r0[idx] + r1[idx];
    }
    __syncthreads();
    const int tg = threadIdx.x >> 6;    // 0..3
    const int c = tg >> 1, hi = tg & 1;
    const int hdl = threadIdx.x & 63;
    const int kloc = c * 16 + hi * 8;
    short8 v;
    for (int j = 0; j < 8; ++j)
        v[j] = (short)f2bf(tile[kloc + j][hdl]);
    const int hd = hd0 + hdl;
    const int h = hd >> 7;
    const int ntd = (hd & 127) >> 5;
    const int l31 = hd & 31;
    size_t pos = ((((size_t)(h * 32 + by) * 4 + ntd) * 2 + c) * 2 + hi) * 32 + l31;
    *(short8*)(&Vfrag[pos * 8]) = v;
}

// ---------------- Flash attention (round-14 + split-accumulator QK) ----------
// KVBLK=32, K/V double-buffered (32KB LDS), stage(t+1) -> compute(t) -> barrier.
// QK^T now uses TWO accumulators (sa: m=0..3, sb: m=4..7) -> dependent-MFMA
// chain of 4 instead of 8; recombined in the exp2 input (v_add feeding v_exp).
// exp2 via raw v_exp_f32 (1 instr guaranteed); psum tree-reduced (depth 4).
// In-register softmax (cvt_pk + permlane32_swap), fragment-order V (0 conflicts),
// s_setprio around MFMA clusters.
__global__ __launch_bounds__(256, 3) void attn(const float* __restrict__ Q,
                                               const unsigned short* __restrict__ Kbf,
                                               const unsigned short* __restrict__ Vfrag,
                                               float* __restrict__ O) {
    __shared__ __align__(16) unsigned short Ks[2][32 * 128];   // [key][d], src-swizzled
    __shared__ __align__(16) unsigned short Vs[2][32 * 128];   // fragment-order, linear
    const int tid = threadIdx.x;
    const int lane = tid & 63;
    const int wave = tid >> 6;
    const int l31 = lane & 31;
    const int hi = lane >> 5;
    const int flat = blockIdx.x + gridDim.x * blockIdx.y;  // gridDim.x = 32
    const int wid = (flat & 7) * 96 + (flat >> 3);          // bijective: 768 = 8*96
    const int h = wid >> 5;
    const int q0 = (wid & 31) * 128 + wave * 32;
    const float qscale = 0.08838834764831843f * 1.44269504088896340736f;  // D^-0.5 * log2(e)
    const float SHIFT = 32.0f;
    const int NT = LK / 32;  // 32 kv-tiles

    // hoist Q B-fragments: lane holds Q[q0+l31][m*16 + hi*8 + j], m=0..7
    short8 qf[8];
#pragma unroll
    for (int m = 0; m < 8; ++m) {
        const float* qp = &Q[(q0 + l31) * HID + h * HD + m * 16 + hi * 8];
        float4 lo = *(const float4*)(qp);
        float4 hif = *(const float4*)(qp + 4);
        short8 v;
        v[0] = (short)f2bf(lo.x * qscale);
        v[1] = (short)f2bf(lo.y * qscale);
        v[2] = (short)f2bf(lo.z * qscale);
        v[3] = (short)f2bf(lo.w * qscale);
        v[4] = (short)f2bf(hif.x * qscale);
        v[5] = (short)f2bf(hif.y * qscale);
        v[6] = (short)f2bf(hif.z * qscale);
        v[7] = (short)f2bf(hif.w * qscale);
        qf[m] = v;
    }

    floatx16 accO[4];
#pragma unroll
    for (int i = 0; i < 4; ++i)
#pragma unroll
        for (int r = 0; r < 16; ++r) accO[i][r] = 0.f;
    float psum = 0.f;

    auto stageK = [&](int b, int kt) {
        for (int i = 0; i < 2; ++i) {
            int slot = i * 256 + tid;             // 512 slots = 32 rows x 16 blocks
            int r = slot >> 4, bb = slot & 15;
            int g = bb ^ (r & 15);
            gload16(&Kbf[(kt * 32 + r) * HID + h * HD + g * 8],
                    &Ks[b][(i * 256 + wave * 64) * 8]);
        }
    };
    auto stageV = [&](int b, int kt) {
        const unsigned short* src = Vfrag + ((size_t)(h * 32 + kt) << 12);  // 8KB tile
        for (int i = 0; i < 2; ++i) {
            int slot = i * 256 + tid;
            gload16(&src[slot * 8], &Vs[b][(i * 256 + wave * 64) * 8]);
        }
    };

    auto compute = [&](int b) {
        floatx16 sa, sb;
#pragma unroll
        for (int r = 0; r < 16; ++r) { sa[r] = -SHIFT; sb[r] = 0.f; }
        // QK^T, split accumulators: two independent chains of 4 dependent MFMAs
        __builtin_amdgcn_s_setprio(1);
#pragma unroll
        for (int m = 0; m < 4; ++m) {
            int ca = m * 2 + hi;
            int cb2 = (m + 4) * 2 + hi;
            int slota = l31 * 16 + (ca ^ (l31 & 15));
            int slotb = l31 * 16 + (cb2 ^ (l31 & 15));
            short8 kfa = *(const short8*)(&Ks[b][slota * 8]);
            short8 kfb = *(const short8*)(&Ks[b][slotb * 8]);
            sa = __builtin_amdgcn_mfma_f32_32x32x16_bf16(kfa, qf[m], sa, 0, 0, 0);
            sb = __builtin_amdgcn_mfma_f32_32x32x16_bf16(kfb, qf[m + 4], sb, 0, 0, 0);
        }
        __builtin_amdgcn_s_setprio(0);
        // softmax: e = exp2(sa+sb); cvt_pk pack; permlane32_swap -> A-fragments
        float e[16];
#pragma unroll
        for (int r = 0; r < 16; ++r) e[r] = fexp2(sa[r] + sb[r]);
        // tree psum (no fast-math: explicit reassociation)
        {
            float s01 = e[0] + e[1],   s23 = e[2] + e[3];
            float s45 = e[4] + e[5],   s67 = e[6] + e[7];
            float s89 = e[8] + e[9],   sab = e[10] + e[11];
            float scd = e[12] + e[13], sef = e[14] + e[15];
            float t0 = s01 + s23, t1 = s45 + s67, t2 = s89 + sab, t3 = scd + sef;
            psum += (t0 + t1) + (t2 + t3);
        }
        unsigned d0 = cvtpk(e[0], e[1]),   d1 = cvtpk(e[2], e[3]);
        unsigned d2 = cvtpk(e[4], e[5]),   d3 = cvtpk(e[6], e[7]);
        unsigned d4 = cvtpk(e[8], e[9]),   d5 = cvtpk(e[10], e[11]);
        unsigned d6 = cvtpk(e[12], e[13]), d7 = cvtpk(e[14], e[15]);
        asm volatile("v_permlane32_swap_b32 %0, %1" : "+v"(d0), "+v"(d2));
        asm volatile("v_permlane32_swap_b32 %0, %1" : "+v"(d1), "+v"(d3));
        asm volatile("v_permlane32_swap_b32 %0, %1" : "+v"(d4), "+v"(d6));
        asm volatile("v_permlane32_swap_b32 %0, %1" : "+v"(d5), "+v"(d7));
        union { unsigned u[4]; short8 s; } p0, p1;
        p0.u[0] = d0; p0.u[1] = d1; p0.u[2] = d2; p0.u[3] = d3;  // keys 0..15
        p1.u[0] = d4; p1.u[1] = d5; p1.u[2] = d6; p1.u[3] = d7;  // keys 16..31
        // O += P V: B-fragment slot = ((ntd*2 + c)*2 + hi)*32 + l31 — conflict-free
        __builtin_amdgcn_s_setprio(1);
#pragma unroll
        for (int ntd = 0; ntd < 4; ++ntd) {
            int s0 = ((ntd * 2 + 0) * 2 + hi) * 32 + l31;
            int s1 = ((ntd * 2 + 1) * 2 + hi) * 32 + l31;
            short8 vf0 = *(const short8*)(&Vs[b][s0 * 8]);
            short8 vf1 = *(const short8*)(&Vs[b][s1 * 8]);
            accO[ntd] = __builtin_amdgcn_mfma_f32_32x32x16_bf16(p0.s, vf0, accO[ntd], 0, 0, 0);
            accO[ntd] = __builtin_amdgcn_mfma_f32_32x32x16_bf16(p1.s, vf1, accO[ntd], 0, 0, 0);
        }
        __builtin_amdgcn_s_setprio(0);
    };

    stageK(0, 0);
    stageV(0, 0);
    __syncthreads();
    int buf = 0;
    for (int t = 0; t < NT - 1; ++t) {
        stageK(buf ^ 1, t + 1);
        stageV(buf ^ 1, t + 1);
        compute(buf);
        __syncthreads();
        buf ^= 1;
    }
    compute(buf);

    // epilogue: psum covers half the keys; partner (lane^32) has the rest
    float s = psum + __shfl_xor(psum, 32);
    float rinv = 1.0f / s;  // valid for q = l31
    float ri[16];
#pragma unroll
    for (int r = 0; r < 16; ++r) {
        int row = (r & 3) + 8 * (r >> 2) + 4 * hi;
        ri[r] = __shfl(rinv, row);
    }
#pragma unroll
    for (int ntd = 0; ntd < 4; ++ntd)
#pragma unroll
        for (int r = 0; r < 16; ++r) {
            int row = (r & 3) + 8 * (r >> 2) + 4 * hi;
            O[(q0 + row) * HID + h * HD + ntd * 32 + l31] = accO[ntd][r] * ri[r];
        }
}

extern "C" void kernel_launch(void* const* d_in, const int* in_sizes, int n_in,
                              void* d_out, int out_size, void* d_ws, size_t ws_size,
                              hipStream_t stream) {
    const float* Q      = (const float*)d_in[0];
    const float* latent = (const float*)d_in[1];
    const float* freqs  = (const float*)d_in[2];
    const float* Wk     = (const float*)d_in[3];
    const float* Wv     = (const float*)d_in[4];
    const float* rmsw   = (const float*)d_in[5];
    float* out = (float*)d_out;
    char* ws = (char*)d_ws;

    // ws layout (62,914,560 bytes; Wv reuses Wk's slot — stream order serializes)
    unsigned short* latent_bf = (unsigned short*)(ws);               //  6,291,456
    unsigned short* Wbf       = (unsigned short*)(ws + 6291456);     // 18,874,368 (Wk, then Wv)
    float*          raw0      = (float*)(ws + 25165824);             // 12,582,912 split-K partial 0
    float*          raw1      = (float*)(ws + 37748736);             // 12,582,912 split-K partial 1
    unsigned short* Kbf       = (unsigned short*)(ws + 50331648);    //  6,291,456
    unsigned short* Vfrag     = (unsigned short*)(ws + 56623104);    //  6,291,456

    f32_to_bf16<<<2048, 256, 0, stream>>>(latent, latent_bf, (LK * HID) / 4);
    f32_to_bf16<<<2048, 256, 0, stream>>>(Wk, Wbf, (HID * HID) / 4);

    gemm_proj<<<dim3(16, 24, 2), 256, 0, stream>>>(latent_bf, Wbf, raw0, LK, HID, HID);
    rmsnorm_rope<<<(LK * NH) / 2, 256, 0, stream>>>(raw0, raw1, freqs, rmsw, Kbf);

    f32_to_bf16<<<2048, 256, 0, stream>>>(Wv, Wbf, (HID * HID) / 4);
    gemm_proj<<<dim3(16, 24, 2), 256, 0, stream>>>(latent_bf, Wbf, raw0, LK, HID, HID);
    transpose_v<<<dim3(HID / 64, LK / 32), 256, 0, stream>>>(raw0, raw1, Vfrag);

    attn<<<dim3(LQ / 128, NH), 256, 0, stream>>>(Q, Kbf, Vfrag, out);
}